// Round 1
// baseline (658.549 us; speedup 1.0000x reference)
//
#include <hip/hip_runtime.h>
#include <cstdint>
#include <cstddef>

typedef unsigned short u16;
typedef unsigned int u32;
typedef __attribute__((ext_vector_type(8))) short short8;
typedef __attribute__((ext_vector_type(4))) float f32x4;

__device__ __forceinline__ float bf2f(u16 v) { return __uint_as_float((u32)v << 16); }
__device__ __forceinline__ u16 f2bf(float f) {
    u32 u = __float_as_uint(f);
    u = (u + 0x7fffu + ((u >> 16) & 1u)) >> 16;   // RNE, finite values only
    return (u16)u;
}

// async global->LDS, 16 B/lane; LDS dest must be wave-uniform base + lane*16
#define GLD16(g, l) __builtin_amdgcn_global_load_lds( \
    (const __attribute__((address_space(1))) void*)(g), \
    (__attribute__((address_space(3))) void*)(l), 16, 0, 0)

// ------------------------------------------------------------------
// Kernel 0: dtype sniffer (flag=1 -> fp32 inputs).
// ------------------------------------------------------------------
__global__ void detect_kernel(const u16* __restrict__ x, int* __restrict__ flag) {
    int cnt = 0;
    for (int i = threadIdx.x; i < 256; i += 64) {
        const int e = (x[2 * i] >> 7) & 0xFF;
        cnt += (e >= 96 && e <= 135) ? 1 : 0;
    }
    #pragma unroll
    for (int o = 32; o; o >>= 1) cnt += __shfl_down(cnt, o, 64);
    if (threadIdx.x == 0) *flag = (cnt < 128) ? 1 : 0;
}

// ------------------------------------------------------------------
// Kernel 1: W [384,768] -> bf16.
// ------------------------------------------------------------------
__global__ void wconv_kernel(const void* __restrict__ w, u16* __restrict__ wbf,
                             const int* __restrict__ flag) {
    const int i = blockIdx.x * 256 + threadIdx.x;
    if (i >= 384 * 768) return;
    if (*flag) wbf[i] = f2bf(((const float*)w)[i]);
    else       wbf[i] = ((const u16*)w)[i];
}

// ------------------------------------------------------------------
// Kernel 2: x_j stencil, pixel-major LDS [3136][8ch].
// xc layout: [b][group 0..95][hw][8c]; groups 0..47 = x, 48..95 = x_j.
// min over 20 neighbors done in pairs -> v_min3_f32 fusion.
// ------------------------------------------------------------------
__global__ __launch_bounds__(256) void xj_kernel(const void* __restrict__ xin,
                                                 u16* __restrict__ xc,
                                                 const int* __restrict__ flag) {
    const int cg = blockIdx.x, b = blockIdx.y;
    const int fp = *flag;
    __shared__ __align__(16) u16 pl[3136][8];
    const size_t plane0 = ((size_t)b * 384 + (size_t)cg * 8) * 3136;

    if (fp) {
        const float* xb = (const float*)xin + plane0;
        for (int g = threadIdx.x; g < 784; g += 256) {
            const int p = g * 4;
            float vv[8][4];
            #pragma unroll
            for (int c = 0; c < 8; ++c) {
                const float4 t = *(const float4*)(xb + (size_t)c * 3136 + p);
                vv[c][0] = t.x; vv[c][1] = t.y; vv[c][2] = t.z; vv[c][3] = t.w;
            }
            #pragma unroll
            for (int i = 0; i < 4; ++i) {
                u32 q[4];
                #pragma unroll
                for (int cc = 0; cc < 4; ++cc)
                    q[cc] = (u32)f2bf(vv[cc * 2][i]) | ((u32)f2bf(vv[cc * 2 + 1][i]) << 16);
                *(uint4*)&pl[p + i][0] = make_uint4(q[0], q[1], q[2], q[3]);
            }
        }
    } else {
        const u16* xb = (const u16*)xin + plane0;
        for (int g = threadIdx.x; g < 784; g += 256) {
            const int p = g * 4;
            u32 rc[8][2];
            #pragma unroll
            for (int c = 0; c < 8; ++c) {
                const uint2 t = *(const uint2*)(xb + (size_t)c * 3136 + p);
                rc[c][0] = t.x; rc[c][1] = t.y;
            }
            #pragma unroll
            for (int i = 0; i < 4; ++i) {
                const int d = i >> 1, sh = (i & 1) * 16;
                u32 q[4];
                #pragma unroll
                for (int cc = 0; cc < 4; ++cc) {
                    const u32 lo = (rc[cc * 2][d] >> sh) & 0xFFFFu;
                    const u32 hi = (rc[cc * 2 + 1][d] >> sh) & 0xFFFFu;
                    q[cc] = lo | (hi << 16);
                }
                *(uint4*)&pl[p + i][0] = make_uint4(q[0], q[1], q[2], q[3]);
            }
        }
    }
    __syncthreads();

    for (int p = threadIdx.x; p < 3136; p += 256) {
        const int h = p / 56, w = p - h * 56;
        int off[20];
        const int S[5] = {1, 3, 7, 15, 31};
        #pragma unroll
        for (int si = 0; si < 5; ++si) {
            const int s = S[si];
            int hp = h + s; if (hp >= 56) hp -= 56;
            int hm = h - s; if (hm < 0)   hm += 56;
            int wp = w + s; if (wp >= 56) wp -= 56;
            int wm = w - s; if (wm < 0)   wm += 56;
            off[si * 4 + 0] = hp * 56 + w;
            off[si * 4 + 1] = hm * 56 + w;
            off[si * 4 + 2] = h * 56 + wp;
            off[si * 4 + 3] = h * 56 + wm;
        }
        const uint4 self = *(const uint4*)&pl[p][0];
        const u32 sw[4] = {self.x, self.y, self.z, self.w};
        float xv[8], mn[8];
        #pragma unroll
        for (int c2 = 0; c2 < 4; ++c2) {
            xv[c2 * 2]     = __uint_as_float(sw[c2] << 16);
            xv[c2 * 2 + 1] = __uint_as_float(sw[c2] & 0xFFFF0000u);
            mn[c2 * 2] = xv[c2 * 2]; mn[c2 * 2 + 1] = xv[c2 * 2 + 1];
        }
        #pragma unroll
        for (int k = 0; k < 20; k += 2) {
            const uint4 na = *(const uint4*)&pl[off[k]][0];
            const uint4 nb = *(const uint4*)&pl[off[k + 1]][0];
            const u32 aw[4] = {na.x, na.y, na.z, na.w};
            const u32 bw[4] = {nb.x, nb.y, nb.z, nb.w};
            #pragma unroll
            for (int c2 = 0; c2 < 4; ++c2) {
                mn[c2 * 2]     = fminf(fminf(__uint_as_float(aw[c2] << 16),
                                             __uint_as_float(bw[c2] << 16)), mn[c2 * 2]);
                mn[c2 * 2 + 1] = fminf(fminf(__uint_as_float(aw[c2] & 0xFFFF0000u),
                                             __uint_as_float(bw[c2] & 0xFFFF0000u)), mn[c2 * 2 + 1]);
            }
        }
        u32 jq[4];
        #pragma unroll
        for (int c2 = 0; c2 < 4; ++c2)
            jq[c2] = (u32)f2bf(xv[c2 * 2] - mn[c2 * 2]) |
                     ((u32)f2bf(xv[c2 * 2 + 1] - mn[c2 * 2 + 1]) << 16);
        u16* px = xc + ((((size_t)b * 96) + cg) * 3136 + p) * 8;
        u16* pj = xc + ((((size_t)b * 96) + 48 + cg) * 3136 + p) * 8;
        *(uint4*)px = self;
        *(uint4*)pj = make_uint4(jq[0], jq[1], jq[2], jq[3]);
    }
}

// ------------------------------------------------------------------
// Kernel 3: Y = Wbf[384,768] @ Xc[768,50176] + BN + exact GELU.
// v2: whole M=384 per block (B staged ONCE), 512 threads = 8 waves each
// owning 48x64 (3x4 frags of mfma 16x16x32). K split into 6 phases of 128,
// B double-buffered via global_load_lds; A-fragments ping-pong prefetched
// one phase ahead into registers. Raw s_barrier + counted s_waitcnt
// vmcnt(N) (never 0 in the loop) keeps next-phase stage + A-prefetch in
// flight across barriers. grid 784, block 512.
// ------------------------------------------------------------------
__global__ __launch_bounds__(512, 8) void gemm_kernel(
        const u16* __restrict__ xc, const u16* __restrict__ Wt,
        const void* __restrict__ cb, const void* __restrict__ bsc,
        const void* __restrict__ bbi, const void* __restrict__ bme,
        const void* __restrict__ bva, void* __restrict__ outp,
        const int* __restrict__ flag) {
    const int ntile = blockIdx.x;             // 0..783
    const int fp = *flag;
    // smem: 2 x 16 KB B buffers (32768 B), reused in epilogue as
    // 8 waves x 16x68 f32 transpose tiles (34816 B). PB separate.
    __shared__ __align__(16) unsigned char smem[34816];
    __shared__ float2 PB[384];
    u16* const smemu = (u16*)smem;

    const int tid = threadIdx.x;
    if (tid < 384) {
        float vsc, vva, vcb, vme, vbi;
        if (fp) {
            vsc = ((const float*)bsc)[tid]; vva = ((const float*)bva)[tid];
            vcb = ((const float*)cb)[tid];  vme = ((const float*)bme)[tid];
            vbi = ((const float*)bbi)[tid];
        } else {
            vsc = bf2f(((const u16*)bsc)[tid]); vva = bf2f(((const u16*)bva)[tid]);
            vcb = bf2f(((const u16*)cb)[tid]);  vme = bf2f(((const u16*)bme)[tid]);
            vbi = bf2f(((const u16*)bbi)[tid]);
        }
        const float seff = vsc * rsqrtf(vva + 1e-5f);
        PB[tid] = make_float2(seff, (vcb - vme) * seff + vbi);
    }

    const int lane = tid & 63, wv = tid >> 6;
    const int quad = lane >> 4, l16 = lane & 15;
    const int bb  = ntile / 49;
    const int hw0 = (ntile - bb * 49) * 64;

    // B staging: phase q covers groups q*16..+16; 1024 16B-chunks, 2/thread.
    const u16* bgp[2]; int bofs[2];
    #pragma unroll
    for (int i = 0; i < 2; ++i) {
        const int idx = i * 512 + tid;        // 0..1023
        const int gg = idx >> 6, n = idx & 63;
        bgp[i]  = xc + (((size_t)bb * 96 + gg) * 3136 + hw0 + n) * 8;
        bofs[i] = idx * 8;
    }
    #define STAGE(q) { \
        u16* dst = smemu + ((q) & 1) * 8192; \
        GLD16(bgp[0] + (size_t)(q) * 16 * 3136 * 8, dst + bofs[0]); \
        GLD16(bgp[1] + (size_t)(q) * 16 * 3136 * 8, dst + bofs[1]); }

    // A-fragment global pointers: row = wv*48 + im*16 + l16
    const u16* arow[3];
    #pragma unroll
    for (int im = 0; im < 3; ++im)
        arow[im] = Wt + (size_t)(wv * 48 + im * 16 + l16) * 768 + quad * 8;

    #define LOADA(dst, q) { \
        _Pragma("unroll") \
        for (int s4 = 0; s4 < 4; ++s4) \
            _Pragma("unroll") \
            for (int im = 0; im < 3; ++im) \
                dst[s4 * 3 + im] = *(const short8*)(arow[im] + (q) * 128 + s4 * 32); }

    #define COMPUTE(q, afv) { \
        const u16* bufq = smemu + ((q) & 1) * 8192; \
        _Pragma("unroll") \
        for (int s = 0; s < 4; ++s) { \
            short8 bfv[4]; \
            _Pragma("unroll") \
            for (int in = 0; in < 4; ++in) \
                bfv[in] = *(const short8*)(bufq + ((s * 4 + quad) * 64 + in * 16 + l16) * 8); \
            _Pragma("unroll") \
            for (int im = 0; im < 3; ++im) \
                _Pragma("unroll") \
                for (int in = 0; in < 4; ++in) \
                    acc[im][in] = __builtin_amdgcn_mfma_f32_16x16x32_bf16( \
                                      afv[s * 3 + im], bfv[in], acc[im][in], 0, 0, 0); } }

    #define VMCNT14 asm volatile("s_waitcnt vmcnt(14)" ::: "memory")
    #define VMCNT12 asm volatile("s_waitcnt vmcnt(12)" ::: "memory")

    f32x4 acc[3][4];
    #pragma unroll
    for (int im = 0; im < 3; ++im)
        #pragma unroll
        for (int in = 0; in < 4; ++in)
            acc[im][in] = {0.f, 0.f, 0.f, 0.f};

    short8 afA[12], afB[12];

    // Prologue: A(0) + stage(0) + stage(1); wait A(0)+stage(0), keep stage(1)
    // in flight; lgkmcnt(0) makes the PB ds_writes visible across the barrier.
    LOADA(afA, 0);
    STAGE(0);
    STAGE(1);
    asm volatile("s_waitcnt vmcnt(2) lgkmcnt(0)" ::: "memory");
    __builtin_amdgcn_s_barrier();

    // Per phase q: issue A(q+1); compute q; barrier (frees buf[q&1]);
    // stage(q+2) into buf[q&1]; counted wait for stage(q+1); barrier.
    // Outstanding at the wait: A(q+1)=12 + stage(q+2)=2 -> vmcnt(14).
    #define PHASE(q, cur, nxt) { \
        if ((q) < 5) LOADA(nxt, (q) + 1); \
        COMPUTE(q, cur); \
        __builtin_amdgcn_s_barrier(); \
        if ((q) < 4) STAGE((q) + 2); \
        if ((q) <= 3)      { VMCNT14; __builtin_amdgcn_s_barrier(); } \
        else if ((q) == 4) { VMCNT12; __builtin_amdgcn_s_barrier(); } }

    PHASE(0, afA, afB);
    PHASE(1, afB, afA);
    PHASE(2, afA, afB);
    PHASE(3, afB, afA);
    PHASE(4, afA, afB);
    PHASE(5, afB, afA);

    // --- epilogue: BN + exact GELU, per-wave LDS transpose, coalesced stores ---
    float* T = (float*)smem + wv * (16 * 68);   // 4352 B/wave, disjoint
    const size_t obase = (size_t)bb * 384 * 3136 + hw0;
    #pragma unroll
    for (int im = 0; im < 3; ++im) {
        #pragma unroll
        for (int r = 0; r < 4; ++r) {
            const float2 sb = PB[(wv * 48 + im * 16 + quad * 4 + r)];
            #pragma unroll
            for (int in = 0; in < 4; ++in) {
                float v = acc[im][in][r] * sb.x + sb.y;
                v = 0.5f * v * (1.0f + erff(v * 0.70710678118654752f));
                T[(quad * 4 + r) * 68 + in * 16 + l16] = v;
            }
        }
        asm volatile("s_waitcnt lgkmcnt(0)" ::: "memory");
        #pragma unroll
        for (int it = 0; it < 4; ++it) {
            const int flat = it * 256 + lane * 4;   // 0..1023
            const int row = flat >> 6, col = flat & 63;
            const float4 vv = *(const float4*)&T[row * 68 + col];
            const size_t oi = obase +
                (size_t)(wv * 48 + im * 16 + row) * 3136 + col;
            if (fp) {
                *(float4*)((float*)outp + oi) = vv;
            } else {
                const u32 a = (u32)f2bf(vv.x) | ((u32)f2bf(vv.y) << 16);
                const u32 b2 = (u32)f2bf(vv.z) | ((u32)f2bf(vv.w) << 16);
                *(uint2*)((u16*)outp + oi) = make_uint2(a, b2);
            }
        }
        asm volatile("s_waitcnt lgkmcnt(0)" ::: "memory");
    }
    #undef PHASE
    #undef VMCNT14
    #undef VMCNT12
    #undef COMPUTE
    #undef LOADA
    #undef STAGE
}

extern "C" void kernel_launch(void* const* d_in, const int* in_sizes, int n_in,
                              void* d_out, int out_size, void* d_ws, size_t ws_size,
                              hipStream_t stream) {
    const void* x   = d_in[0];
    const void* w   = d_in[1];
    const void* cbp = d_in[2];
    const void* bsc = d_in[3];
    const void* bbi = d_in[4];
    const void* bme = d_in[5];
    const void* bva = d_in[6];

    int* flag = (int*)d_ws;
    u16* xc   = (u16*)((char*)d_ws + 64);            // 77,070,336 B
    u16* wbf  = xc + (size_t)16 * 96 * 3136 * 8;     // 589,824 B

    detect_kernel<<<1, 64, 0, stream>>>((const u16*)x, flag);
    wconv_kernel<<<1152, 256, 0, stream>>>(w, wbf, flag);
    xj_kernel<<<dim3(48, 16), 256, 0, stream>>>(x, xc, flag);
    gemm_kernel<<<784, 512, 0, stream>>>(xc, wbf, cbp, bsc, bbi, bme, bva,
                                         d_out, flag);
}

// Round 2
// 285.634 us; speedup vs baseline: 2.3056x; 2.3056x over previous
//
#include <hip/hip_runtime.h>
#include <cstdint>
#include <cstddef>

typedef unsigned short u16;
typedef unsigned int u32;
typedef __attribute__((ext_vector_type(8))) short short8;
typedef __attribute__((ext_vector_type(4))) float f32x4;

__device__ __forceinline__ float bf2f(u16 v) { return __uint_as_float((u32)v << 16); }
__device__ __forceinline__ u16 f2bf(float f) {
    u32 u = __float_as_uint(f);
    u = (u + 0x7fffu + ((u >> 16) & 1u)) >> 16;   // RNE, finite values only
    return (u16)u;
}

// async global->LDS, 16 B/lane; LDS dest must be wave-uniform base + lane*16
#define GLD16(g, l) __builtin_amdgcn_global_load_lds( \
    (const __attribute__((address_space(1))) void*)(g), \
    (__attribute__((address_space(3))) void*)(l), 16, 0, 0)

// ------------------------------------------------------------------
// Kernel 0: dtype sniffer (flag=1 -> fp32 inputs).
// ------------------------------------------------------------------
__global__ void detect_kernel(const u16* __restrict__ x, int* __restrict__ flag) {
    int cnt = 0;
    for (int i = threadIdx.x; i < 256; i += 64) {
        const int e = (x[2 * i] >> 7) & 0xFF;
        cnt += (e >= 96 && e <= 135) ? 1 : 0;
    }
    #pragma unroll
    for (int o = 32; o; o >>= 1) cnt += __shfl_down(cnt, o, 64);
    if (threadIdx.x == 0) *flag = (cnt < 128) ? 1 : 0;
}

// ------------------------------------------------------------------
// Kernel 1: W [384,768] -> bf16.
// ------------------------------------------------------------------
__global__ void wconv_kernel(const void* __restrict__ w, u16* __restrict__ wbf,
                             const int* __restrict__ flag) {
    const int i = blockIdx.x * 256 + threadIdx.x;
    if (i >= 384 * 768) return;
    if (*flag) wbf[i] = f2bf(((const float*)w)[i]);
    else       wbf[i] = ((const u16*)w)[i];
}

// ------------------------------------------------------------------
// Kernel 2: x_j stencil, pixel-major LDS [3136][8ch].
// xc layout: [b][group 0..95][hw][8c]; groups 0..47 = x, 48..95 = x_j.
// min over 20 neighbors done in pairs -> v_min3_f32 fusion.
// ------------------------------------------------------------------
__global__ __launch_bounds__(256) void xj_kernel(const void* __restrict__ xin,
                                                 u16* __restrict__ xc,
                                                 const int* __restrict__ flag) {
    const int cg = blockIdx.x, b = blockIdx.y;
    const int fp = *flag;
    __shared__ __align__(16) u16 pl[3136][8];
    const size_t plane0 = ((size_t)b * 384 + (size_t)cg * 8) * 3136;

    if (fp) {
        const float* xb = (const float*)xin + plane0;
        for (int g = threadIdx.x; g < 784; g += 256) {
            const int p = g * 4;
            float vv[8][4];
            #pragma unroll
            for (int c = 0; c < 8; ++c) {
                const float4 t = *(const float4*)(xb + (size_t)c * 3136 + p);
                vv[c][0] = t.x; vv[c][1] = t.y; vv[c][2] = t.z; vv[c][3] = t.w;
            }
            #pragma unroll
            for (int i = 0; i < 4; ++i) {
                u32 q[4];
                #pragma unroll
                for (int cc = 0; cc < 4; ++cc)
                    q[cc] = (u32)f2bf(vv[cc * 2][i]) | ((u32)f2bf(vv[cc * 2 + 1][i]) << 16);
                *(uint4*)&pl[p + i][0] = make_uint4(q[0], q[1], q[2], q[3]);
            }
        }
    } else {
        const u16* xb = (const u16*)xin + plane0;
        for (int g = threadIdx.x; g < 784; g += 256) {
            const int p = g * 4;
            u32 rc[8][2];
            #pragma unroll
            for (int c = 0; c < 8; ++c) {
                const uint2 t = *(const uint2*)(xb + (size_t)c * 3136 + p);
                rc[c][0] = t.x; rc[c][1] = t.y;
            }
            #pragma unroll
            for (int i = 0; i < 4; ++i) {
                const int d = i >> 1, sh = (i & 1) * 16;
                u32 q[4];
                #pragma unroll
                for (int cc = 0; cc < 4; ++cc) {
                    const u32 lo = (rc[cc * 2][d] >> sh) & 0xFFFFu;
                    const u32 hi = (rc[cc * 2 + 1][d] >> sh) & 0xFFFFu;
                    q[cc] = lo | (hi << 16);
                }
                *(uint4*)&pl[p + i][0] = make_uint4(q[0], q[1], q[2], q[3]);
            }
        }
    }
    __syncthreads();

    for (int p = threadIdx.x; p < 3136; p += 256) {
        const int h = p / 56, w = p - h * 56;
        int off[20];
        const int S[5] = {1, 3, 7, 15, 31};
        #pragma unroll
        for (int si = 0; si < 5; ++si) {
            const int s = S[si];
            int hp = h + s; if (hp >= 56) hp -= 56;
            int hm = h - s; if (hm < 0)   hm += 56;
            int wp = w + s; if (wp >= 56) wp -= 56;
            int wm = w - s; if (wm < 0)   wm += 56;
            off[si * 4 + 0] = hp * 56 + w;
            off[si * 4 + 1] = hm * 56 + w;
            off[si * 4 + 2] = h * 56 + wp;
            off[si * 4 + 3] = h * 56 + wm;
        }
        const uint4 self = *(const uint4*)&pl[p][0];
        const u32 sw[4] = {self.x, self.y, self.z, self.w};
        float xv[8], mn[8];
        #pragma unroll
        for (int c2 = 0; c2 < 4; ++c2) {
            xv[c2 * 2]     = __uint_as_float(sw[c2] << 16);
            xv[c2 * 2 + 1] = __uint_as_float(sw[c2] & 0xFFFF0000u);
            mn[c2 * 2] = xv[c2 * 2]; mn[c2 * 2 + 1] = xv[c2 * 2 + 1];
        }
        #pragma unroll
        for (int k = 0; k < 20; k += 2) {
            const uint4 na = *(const uint4*)&pl[off[k]][0];
            const uint4 nb = *(const uint4*)&pl[off[k + 1]][0];
            const u32 aw[4] = {na.x, na.y, na.z, na.w};
            const u32 bw[4] = {nb.x, nb.y, nb.z, nb.w};
            #pragma unroll
            for (int c2 = 0; c2 < 4; ++c2) {
                mn[c2 * 2]     = fminf(fminf(__uint_as_float(aw[c2] << 16),
                                             __uint_as_float(bw[c2] << 16)), mn[c2 * 2]);
                mn[c2 * 2 + 1] = fminf(fminf(__uint_as_float(aw[c2] & 0xFFFF0000u),
                                             __uint_as_float(bw[c2] & 0xFFFF0000u)), mn[c2 * 2 + 1]);
            }
        }
        u32 jq[4];
        #pragma unroll
        for (int c2 = 0; c2 < 4; ++c2)
            jq[c2] = (u32)f2bf(xv[c2 * 2] - mn[c2 * 2]) |
                     ((u32)f2bf(xv[c2 * 2 + 1] - mn[c2 * 2 + 1]) << 16);
        u16* px = xc + ((((size_t)b * 96) + cg) * 3136 + p) * 8;
        u16* pj = xc + ((((size_t)b * 96) + 48 + cg) * 3136 + p) * 8;
        *(uint4*)px = self;
        *(uint4*)pj = make_uint4(jq[0], jq[1], jq[2], jq[3]);
    }
}

// ------------------------------------------------------------------
// Kernel 3: Y = Wbf[384,768] @ Xc[768,50176] + BN + exact GELU.
// v3 = v2 schedule with the register-budget fix:
//   __launch_bounds__(512, 2)  (v2's (512,8) forced a 64-VGPR cap ->
//   ~190 VGPRs of state spilled to scratch, 1.9 GB of scratch traffic,
//   510 us). 2 waves/SIMD with ~190 VGPRs: no spill; latency hidden by
//   the counted-vmcnt pipeline (ILP), not TLP.
// Whole M=384 per block (B staged ONCE); 512 threads = 8 waves each
// owning 48x64 (3x4 frags of mfma 16x16x32). K in 6 phases of 128,
// B double-buffered via global_load_lds; A ping-pong prefetched one
// phase ahead into registers. Raw s_barrier + counted vmcnt (never 0
// in the loop). s_setprio(1) around each 12-MFMA cluster (T5).
// grid 784, block 512.
// ------------------------------------------------------------------
__global__ __launch_bounds__(512, 2) void gemm_kernel(
        const u16* __restrict__ xc, const u16* __restrict__ Wt,
        const void* __restrict__ cb, const void* __restrict__ bsc,
        const void* __restrict__ bbi, const void* __restrict__ bme,
        const void* __restrict__ bva, void* __restrict__ outp,
        const int* __restrict__ flag) {
    const int ntile = blockIdx.x;             // 0..783
    const int fp = *flag;
    // smem: 2 x 16 KB B buffers (32768 B), reused in epilogue as
    // 8 waves x 16x68 f32 transpose tiles (34816 B). PB separate.
    __shared__ __align__(16) unsigned char smem[34816];
    __shared__ float2 PB[384];
    u16* const smemu = (u16*)smem;

    const int tid = threadIdx.x;
    if (tid < 384) {
        float vsc, vva, vcb, vme, vbi;
        if (fp) {
            vsc = ((const float*)bsc)[tid]; vva = ((const float*)bva)[tid];
            vcb = ((const float*)cb)[tid];  vme = ((const float*)bme)[tid];
            vbi = ((const float*)bbi)[tid];
        } else {
            vsc = bf2f(((const u16*)bsc)[tid]); vva = bf2f(((const u16*)bva)[tid]);
            vcb = bf2f(((const u16*)cb)[tid]);  vme = bf2f(((const u16*)bme)[tid]);
            vbi = bf2f(((const u16*)bbi)[tid]);
        }
        const float seff = vsc * rsqrtf(vva + 1e-5f);
        PB[tid] = make_float2(seff, (vcb - vme) * seff + vbi);
    }

    const int lane = tid & 63, wv = tid >> 6;
    const int quad = lane >> 4, l16 = lane & 15;
    const int bb  = ntile / 49;
    const int hw0 = (ntile - bb * 49) * 64;

    // B staging: phase q covers groups q*16..+16; 1024 16B-chunks, 2/thread.
    const u16* bgp[2]; int bofs[2];
    #pragma unroll
    for (int i = 0; i < 2; ++i) {
        const int idx = i * 512 + tid;        // 0..1023
        const int gg = idx >> 6, n = idx & 63;
        bgp[i]  = xc + (((size_t)bb * 96 + gg) * 3136 + hw0 + n) * 8;
        bofs[i] = idx * 8;
    }
    #define STAGE(q) { \
        u16* dst = smemu + ((q) & 1) * 8192; \
        GLD16(bgp[0] + (size_t)(q) * 16 * 3136 * 8, dst + bofs[0]); \
        GLD16(bgp[1] + (size_t)(q) * 16 * 3136 * 8, dst + bofs[1]); }

    // A-fragment global pointers: row = wv*48 + im*16 + l16
    const u16* arow[3];
    #pragma unroll
    for (int im = 0; im < 3; ++im)
        arow[im] = Wt + (size_t)(wv * 48 + im * 16 + l16) * 768 + quad * 8;

    #define LOADA(dst, q) { \
        _Pragma("unroll") \
        for (int s4 = 0; s4 < 4; ++s4) \
            _Pragma("unroll") \
            for (int im = 0; im < 3; ++im) \
                dst[s4 * 3 + im] = *(const short8*)(arow[im] + (q) * 128 + s4 * 32); }

    #define COMPUTE(q, afv) { \
        const u16* bufq = smemu + ((q) & 1) * 8192; \
        _Pragma("unroll") \
        for (int s = 0; s < 4; ++s) { \
            short8 bfv[4]; \
            _Pragma("unroll") \
            for (int in = 0; in < 4; ++in) \
                bfv[in] = *(const short8*)(bufq + ((s * 4 + quad) * 64 + in * 16 + l16) * 8); \
            __builtin_amdgcn_s_setprio(1); \
            _Pragma("unroll") \
            for (int im = 0; im < 3; ++im) \
                _Pragma("unroll") \
                for (int in = 0; in < 4; ++in) \
                    acc[im][in] = __builtin_amdgcn_mfma_f32_16x16x32_bf16( \
                                      afv[s * 3 + im], bfv[in], acc[im][in], 0, 0, 0); \
            __builtin_amdgcn_s_setprio(0); } }

    #define VMCNT14 asm volatile("s_waitcnt vmcnt(14)" ::: "memory")
    #define VMCNT12 asm volatile("s_waitcnt vmcnt(12)" ::: "memory")

    f32x4 acc[3][4];
    #pragma unroll
    for (int im = 0; im < 3; ++im)
        #pragma unroll
        for (int in = 0; in < 4; ++in)
            acc[im][in] = {0.f, 0.f, 0.f, 0.f};

    short8 afA[12], afB[12];

    // Prologue: A(0) + stage(0) + stage(1); wait A(0)+stage(0), keep stage(1)
    // in flight; lgkmcnt(0) makes the PB ds_writes visible across the barrier.
    LOADA(afA, 0);
    STAGE(0);
    STAGE(1);
    asm volatile("s_waitcnt vmcnt(2) lgkmcnt(0)" ::: "memory");
    __builtin_amdgcn_s_barrier();

    // Per phase q: issue A(q+1); compute q; barrier (frees buf[q&1]);
    // stage(q+2) into buf[q&1]; counted wait for stage(q+1); barrier.
    // Outstanding at the wait: A(q+1)=12 + stage(q+2)=2 -> vmcnt(14).
    #define PHASE(q, cur, nxt) { \
        if ((q) < 5) LOADA(nxt, (q) + 1); \
        COMPUTE(q, cur); \
        __builtin_amdgcn_s_barrier(); \
        if ((q) < 4) STAGE((q) + 2); \
        if ((q) <= 3)      { VMCNT14; __builtin_amdgcn_s_barrier(); } \
        else if ((q) == 4) { VMCNT12; __builtin_amdgcn_s_barrier(); } }

    PHASE(0, afA, afB);
    PHASE(1, afB, afA);
    PHASE(2, afA, afB);
    PHASE(3, afB, afA);
    PHASE(4, afA, afB);
    PHASE(5, afB, afA);

    // --- epilogue: BN + exact GELU, per-wave LDS transpose, coalesced stores ---
    float* T = (float*)smem + wv * (16 * 68);   // 4352 B/wave, disjoint
    const size_t obase = (size_t)bb * 384 * 3136 + hw0;
    #pragma unroll
    for (int im = 0; im < 3; ++im) {
        #pragma unroll
        for (int r = 0; r < 4; ++r) {
            const float2 sb = PB[(wv * 48 + im * 16 + quad * 4 + r)];
            #pragma unroll
            for (int in = 0; in < 4; ++in) {
                float v = acc[im][in][r] * sb.x + sb.y;
                v = 0.5f * v * (1.0f + erff(v * 0.70710678118654752f));
                T[(quad * 4 + r) * 68 + in * 16 + l16] = v;
            }
        }
        asm volatile("s_waitcnt lgkmcnt(0)" ::: "memory");
        #pragma unroll
        for (int it = 0; it < 4; ++it) {
            const int flat = it * 256 + lane * 4;   // 0..1023
            const int row = flat >> 6, col = flat & 63;
            const float4 vv = *(const float4*)&T[row * 68 + col];
            const size_t oi = obase +
                (size_t)(wv * 48 + im * 16 + row) * 3136 + col;
            if (fp) {
                *(float4*)((float*)outp + oi) = vv;
            } else {
                const u32 a = (u32)f2bf(vv.x) | ((u32)f2bf(vv.y) << 16);
                const u32 b2 = (u32)f2bf(vv.z) | ((u32)f2bf(vv.w) << 16);
                *(uint2*)((u16*)outp + oi) = make_uint2(a, b2);
            }
        }
        asm volatile("s_waitcnt lgkmcnt(0)" ::: "memory");
    }
    #undef PHASE
    #undef VMCNT14
    #undef VMCNT12
    #undef COMPUTE
    #undef LOADA
    #undef STAGE
}

extern "C" void kernel_launch(void* const* d_in, const int* in_sizes, int n_in,
                              void* d_out, int out_size, void* d_ws, size_t ws_size,
                              hipStream_t stream) {
    const void* x   = d_in[0];
    const void* w   = d_in[1];
    const void* cbp = d_in[2];
    const void* bsc = d_in[3];
    const void* bbi = d_in[4];
    const void* bme = d_in[5];
    const void* bva = d_in[6];

    int* flag = (int*)d_ws;
    u16* xc   = (u16*)((char*)d_ws + 64);            // 77,070,336 B
    u16* wbf  = xc + (size_t)16 * 96 * 3136 * 8;     // 589,824 B

    detect_kernel<<<1, 64, 0, stream>>>((const u16*)x, flag);
    wconv_kernel<<<1152, 256, 0, stream>>>(w, wbf, flag);
    xj_kernel<<<dim3(48, 16), 256, 0, stream>>>(x, xc, flag);
    gemm_kernel<<<784, 512, 0, stream>>>(xc, wbf, cbp, bsc, bbi, bme, bva,
                                         d_out, flag);
}